// Round 8
// baseline (475.733 us; speedup 1.0000x reference)
//
#include <hip/hip_runtime.h>
#include <hip/hip_bf16.h>

// out[r, n] = relu( sum_k concat[r,k] * W[k,n] ),
// concat = [review_row | user_row[perm_u] | item_row[perm_i]]
// WT has W's rows pre-permuted so gathers are contiguous rows.
//
// v8.1 (compile fix of v8): __builtin_nontemporal_load requires
//   scalar/ext-vector pointer types; HIP's float4 is a class. All nt
//   accesses now go through the clang ext_vector f32x4 typedef.
//
// v8 rationale: non-temporal hints on the single-touch streams.
//   review loads, adj loads, out stores (and prep's f32 table reads) are nt:
//   they sweep 500+ MB/iter through the 256MB L3 and evict the 19.2MB bf16
//   gather tables (v3 counters: FETCH 364MB vs ~302MB compulsory = table
//   re-fetch from HBM). nt keeps tables L2/L3-resident -> gathers stay
//   cache-hits, HBM fetch drops to compulsory.

#define DIMS 64
#define K3 192
#define MTILE 128      // rows per block (16 per wave, 8 waves)
#define NTHREADS 512
#define LDST 208       // LDS row stride in bf16 units (192 + 16 pad)
#define TBS 68         // epilogue transpose-buffer row stride (floats)

typedef float f32x4 __attribute__((ext_vector_type(4)));
typedef short s16x8 __attribute__((ext_vector_type(8)));
typedef __bf16 bf16x8 __attribute__((ext_vector_type(8)));

__device__ __forceinline__ short f2bf(float f) {
    union { float f; unsigned int u; } v; v.f = f;
    unsigned int u = v.u;
    u += 0x7fffu + ((u >> 16) & 1u);   // round-to-nearest-even
    return (short)(u >> 16);
}

__device__ __forceinline__ void wt_part(const float* __restrict__ W,
                                        const int* __restrict__ perm_u,
                                        const int* __restrict__ perm_i,
                                        short* __restrict__ WT,
                                        int wtb, int t) {
    #pragma unroll
    for (int i = 0; i < 8; ++i) {
        int e = t + (wtb * 8 + i) * 256;  // 0..12287 over 6 blocks
        int k = e >> 6;                   // 0..191
        int n = e & 63;
        float w = W[e];                   // coalesced
        int dk;
        if (k < 64)       dk = k;
        else if (k < 128) dk = 64 + perm_u[k - 64];
        else              dk = 128 + perm_i[k - 128];
        WT[n * K3 + dk] = f2bf(w);
    }
}

// Fallback (small workspace): WT only, 6 blocks of 256.
__global__ void prep_WT(const float* __restrict__ W,
                        const int* __restrict__ perm_u,
                        const int* __restrict__ perm_i,
                        short* __restrict__ WT) {
    wt_part(W, perm_u, perm_i, WT, blockIdx.x, threadIdx.x);
}

// Merged prep: blocks [0, tabBlocks) convert user+item tables f32->bf16;
// blocks [tabBlocks, tabBlocks+6) build WT. One launch, fully parallel.
__global__ void prep_all(const float* __restrict__ W,
                         const int* __restrict__ perm_u,
                         const int* __restrict__ perm_i,
                         const float* __restrict__ user,
                         const float* __restrict__ item,
                         short* __restrict__ WT,
                         short* __restrict__ ub, short* __restrict__ ib,
                         int nu, int ni, int tabBlocks) {
    const int t = threadIdx.x;
    const int b = blockIdx.x;
    if (b >= tabBlocks) {
        wt_part(W, perm_u, perm_i, WT, b - tabBlocks, t);
        return;
    }
    int i8 = (b * 256 + t) * 8;
    const float* src;
    short* dst;
    if (i8 < nu) {
        src = user + i8; dst = ub + i8;
    } else {
        int j = i8 - nu;
        if (j >= ni) return;
        src = item + j; dst = ib + j;
    }
    // f32 originals are never read again -> nt (don't evict bf16 tables)
    f32x4 a = __builtin_nontemporal_load((const f32x4*)src);
    f32x4 c = __builtin_nontemporal_load((const f32x4*)src + 1);
    s16x8 r;
    r[0] = f2bf(a.x); r[1] = f2bf(a.y); r[2] = f2bf(a.z); r[3] = f2bf(a.w);
    r[4] = f2bf(c.x); r[5] = f2bf(c.y); r[6] = f2bf(c.z); r[7] = f2bf(c.w);
    *(s16x8*)dst = r;   // bf16 tables: cacheable (they ARE the reuse)
}

__device__ __forceinline__ bf16x8 pack8(f32x4 a, f32x4 b) {
    bf16x8 r;   // native casts -> v_cvt_pk_bf16_f32 (RNE, same numerics)
    r[0] = (__bf16)a.x; r[1] = (__bf16)a.y; r[2] = (__bf16)a.z; r[3] = (__bf16)a.w;
    r[4] = (__bf16)b.x; r[5] = (__bf16)b.y; r[6] = (__bf16)b.z; r[7] = (__bf16)b.w;
    return r;
}

template<int TAB>
__global__ __launch_bounds__(NTHREADS, 6) void concat_agg_kernel(
        const float* __restrict__ review,
        const float* __restrict__ user,
        const float* __restrict__ item,
        const short* __restrict__ ub,    // bf16 user table (TAB=1)
        const short* __restrict__ ib,    // bf16 item table (TAB=1)
        const int* __restrict__ uadj,
        const int* __restrict__ iadj,
        const short* __restrict__ WT,    // bf16 bits, [64][192] packed
        float* __restrict__ out,
        int n_reviews) {
    // Phase 1 (GEMM): first 26624 B hold ldsW.
    // Phase 2 (epilogue, after barrier): 8 waves x 16 rows x TBS floats.
    __shared__ float ldsF[8 * 16 * TBS];          // 34816 B
    short* ldsW = (short*)ldsF;

    const int t    = threadIdx.x;
    const int lane = t & 63;
    const int wv   = t >> 6;          // 0..7
    const int m    = lane & 15;
    const int q    = lane >> 4;       // 0..3
    const int r0   = blockIdx.x * MTILE;

    int row = r0 + wv * 16 + m;       // per-lane A-fragment row
    if (row >= n_reviews) row = n_reviews - 1;

    // adjacency first: latency hides under WT staging + barrier (nt: read-once)
    const int u  = __builtin_nontemporal_load(uadj + row);
    const int it = __builtin_nontemporal_load(iadj + row);

    // --- stage WT once per block (1536 chunks of 8 bf16; 3 per thread) ---
    #pragma unroll
    for (int i = 0; i < 3; ++i) {
        int c = t + i * NTHREADS;
        int n = c / 24;
        int k = (c - n * 24) * 8;
        *(s16x8*)&ldsW[n * LDST + k] = *(const s16x8*)(WT + c * 8);
    }

    __syncthreads();   // ldsW ready; X loads issue AFTER this (no vmcnt(0) drain)

    // --- X loads in fragment layout; review is single-touch -> nt ---
    const float* rv = review + (size_t)row * DIMS + q * 8;
    f32x4 x0 = __builtin_nontemporal_load((const f32x4*)rv);
    f32x4 x1 = __builtin_nontemporal_load((const f32x4*)rv + 1);
    f32x4 x2 = __builtin_nontemporal_load((const f32x4*)(rv + 32));
    f32x4 x3 = __builtin_nontemporal_load((const f32x4*)(rv + 32) + 1);

    bf16x8 a2, a3, a4, a5;
    if (TAB) {
        const short* uvp = ub + (size_t)u  * DIMS + q * 8;
        const short* ivp = ib + (size_t)it * DIMS + q * 8;
        a2 = __builtin_bit_cast(bf16x8, *(const s16x8*)uvp);
        a3 = __builtin_bit_cast(bf16x8, *(const s16x8*)(uvp + 32));
        a4 = __builtin_bit_cast(bf16x8, *(const s16x8*)ivp);
        a5 = __builtin_bit_cast(bf16x8, *(const s16x8*)(ivp + 32));
    } else {
        const float* uv = user + (size_t)u  * DIMS + q * 8;
        const float* iv = item + (size_t)it * DIMS + q * 8;
        f32x4 u0 = ((const f32x4*)uv)[0],        u1 = ((const f32x4*)uv)[1];
        f32x4 u2 = ((const f32x4*)(uv + 32))[0], u3 = ((const f32x4*)(uv + 32))[1];
        f32x4 i0 = ((const f32x4*)iv)[0],        i1 = ((const f32x4*)iv)[1];
        f32x4 i2 = ((const f32x4*)(iv + 32))[0], i3 = ((const f32x4*)(iv + 32))[1];
        a2 = pack8(u0, u1); a3 = pack8(u2, u3);
        a4 = pack8(i0, i1); a5 = pack8(i2, i3);
    }
    bf16x8 a0 = pack8(x0, x1);
    bf16x8 a1 = pack8(x2, x3);

    const short* wb0 = &ldsW[m * LDST + q * 8];

    f32x4 acc0 = {0.f,0.f,0.f,0.f}, acc1 = {0.f,0.f,0.f,0.f};
    f32x4 acc2 = {0.f,0.f,0.f,0.f}, acc3 = {0.f,0.f,0.f,0.f};

    #define KSTEP(A, KS) do { \
        bf16x8 b0 = __builtin_bit_cast(bf16x8, *(const s16x8*)(wb0 + 0 * 16 * LDST + (KS) * 32)); \
        bf16x8 b1 = __builtin_bit_cast(bf16x8, *(const s16x8*)(wb0 + 1 * 16 * LDST + (KS) * 32)); \
        bf16x8 b2 = __builtin_bit_cast(bf16x8, *(const s16x8*)(wb0 + 2 * 16 * LDST + (KS) * 32)); \
        bf16x8 b3 = __builtin_bit_cast(bf16x8, *(const s16x8*)(wb0 + 3 * 16 * LDST + (KS) * 32)); \
        acc0 = __builtin_amdgcn_mfma_f32_16x16x32_bf16((A), b0, acc0, 0, 0, 0); \
        acc1 = __builtin_amdgcn_mfma_f32_16x16x32_bf16((A), b1, acc1, 0, 0, 0); \
        acc2 = __builtin_amdgcn_mfma_f32_16x16x32_bf16((A), b2, acc2, 0, 0, 0); \
        acc3 = __builtin_amdgcn_mfma_f32_16x16x32_bf16((A), b3, acc3, 0, 0, 0); \
    } while (0)

    KSTEP(a0, 0);
    KSTEP(a1, 1);
    KSTEP(a2, 2);
    KSTEP(a3, 3);
    KSTEP(a4, 4);
    KSTEP(a5, 5);
    #undef KSTEP

    // --- epilogue: transpose through LDS, store dwordx4 (nt: write-once) ---
    __syncthreads();   // all waves done reading ldsW; safe to reuse

    float* tb = ldsF + wv * (16 * TBS);   // private per-wave slice
    #pragma unroll
    for (int v = 0; v < 4; ++v) {
        const int rr = q * 4 + v;
        tb[rr * TBS + m +  0] = fmaxf(acc0[v], 0.0f);
        tb[rr * TBS + m + 16] = fmaxf(acc1[v], 0.0f);
        tb[rr * TBS + m + 32] = fmaxf(acc2[v], 0.0f);
        tb[rr * TBS + m + 48] = fmaxf(acc3[v], 0.0f);
    }
    const int scol = m * 4;
    #pragma unroll
    for (int k = 0; k < 4; ++k) {
        const int lr = 4 * k + q;
        f32x4 o = *(const f32x4*)&tb[lr * TBS + scol];
        const int grow = r0 + wv * 16 + lr;
        if (grow < n_reviews)
            __builtin_nontemporal_store(o, (f32x4*)(out + (size_t)grow * DIMS + scol));
    }
}

extern "C" void kernel_launch(void* const* d_in, const int* in_sizes, int n_in,
                              void* d_out, int out_size, void* d_ws, size_t ws_size,
                              hipStream_t stream) {
    (void)n_in; (void)out_size;
    const float* review = (const float*)d_in[0];
    const float* user   = (const float*)d_in[1];
    const float* item   = (const float*)d_in[2];
    const float* W      = (const float*)d_in[3];
    const int* uadj     = (const int*)d_in[4];
    const int* iadj     = (const int*)d_in[5];
    const int* perm_u   = (const int*)d_in[6];
    const int* perm_i   = (const int*)d_in[7];
    float* out = (float*)d_out;

    const int n_reviews = in_sizes[0] / DIMS;
    const int nu = in_sizes[1];    // user table float count (100000*64)
    const int ni = in_sizes[2];    // item table float count (50000*64)

    short* WT = (short*)d_ws;      // 24576 B at offset 0
    const size_t off_ub = 32768;
    const size_t need = off_ub + (size_t)(nu + ni) * sizeof(short);

    const int grid = (n_reviews + MTILE - 1) / MTILE;

    if (ws_size >= need) {
        short* UB = (short*)((char*)d_ws + off_ub);
        short* IB = UB + nu;
        const int tabBlocks = (nu + ni + 2047) / 2048;   // 8 elems/thread
        prep_all<<<tabBlocks + 6, 256, 0, stream>>>(W, perm_u, perm_i, user, item,
                                                    WT, UB, IB, nu, ni, tabBlocks);
        concat_agg_kernel<1><<<grid, NTHREADS, 0, stream>>>(review, user, item, UB, IB,
                                                            uadj, iadj, WT, out, n_reviews);
    } else {
        prep_WT<<<6, 256, 0, stream>>>(W, perm_u, perm_i, WT);
        concat_agg_kernel<0><<<grid, NTHREADS, 0, stream>>>(review, user, item, nullptr, nullptr,
                                                            uadj, iadj, WT, out, n_reviews);
    }
}